// Round 5
// baseline (784.813 us; speedup 1.0000x reference)
//
#include <hip/hip_runtime.h>

#define BATCH   512
#define GB      4                    // batches per block, carried on MFMA D-rows
#define NBLK    (BATCH / GB)         // 128 blocks, 4 waves each -> 1 wave/SIMD
#define TSTEPS  3600
#define H       64
#define XCHUNK  16
#define NCHUNK  (TSTEPS / XCHUNK)    // 225
#define CLASSES 5

typedef _Float16 half8 __attribute__((ext_vector_type(8)));
typedef float    f32x4 __attribute__((ext_vector_type(4)));

#define L2E 1.44269504088896f
#define S_N (2.0f * L2E)

__device__ __forceinline__ half8 bc_h8(uint4 v) { return __builtin_bit_cast(half8, v); }

// R4 + chain shaves. R4 budget (468 cyc/step, per-CU-normalized): LDS-RT+
// barrier ~210 (structural: the h exchange is all-to-all across waves),
// VALU ~154 (2x my model: bpermute x-path, movs, staging), MFMA ~100
// (dependent K-half chains put 2x MFMA latency on the r-path). This round:
// (1) x held in per-lane registers, one chunk ahead (4x f32x4 double-
// buffered, uniform if(tc&1) swap; compile-time indexing only) -> the
// per-step bpermute (a DS op sharing lgkmcnt with the critical A-reads!),
// cndmask, staging copies and Cr/Cz movs all vanish; proj fmas write the
// MFMA C element directly under the ds_read shadow. (2) all three gates'
// K-half MFMAs made independent (add in tail): removes one MFMA latency
// from the r-path that heads the serial r->n->h chain; z/n adds sit in
// slack. Structure (ownership, LDS layout, head) unchanged from R4.
__global__ __launch_bounds__(256, 1) void gru_mfma_kernel(
    const float* __restrict__ x,      // [B, T, 1]
    const float* __restrict__ w_ih,   // [192, 1]
    const float* __restrict__ w_hh,   // [192, 64]
    const float* __restrict__ b_ih,   // [192]
    const float* __restrict__ b_hh,   // [192]
    const float* __restrict__ w_head, // [5, 64]
    const float* __restrict__ b_head, // [5]
    float* __restrict__ out)          // [B, 5]
{
    // [parity][batch*80 f16]: batch stride 160B, parity stride 640B
    __shared__ __align__(16) _Float16 hB[2][GB * 80];
    __shared__ float hf[GB][H];

    const int tid  = threadIdx.x;
    const int w    = tid >> 6;        // wave id: gate tiles {w, 4+w, 8+w}
    const int lane = tid & 63;
    const int q    = lane >> 4;       // this lane's BATCH (D rows 4q..4q+3)
    const int col  = lane & 15;       // tile column
    const int b0   = blockIdx.x * GB;
    const int i    = 16 * w + col;    // this lane's hidden index

    // --- B fragments: gate tiles {w, 4+w, 8+w}, f16, exp2-pre-scaled.
    half8 wR[2], wZ[2], wN[2];
#pragma unroll
    for (int c = 0; c < 2; ++c) {
        const float* pr = w_hh + (16 * w       + col) * H + 32 * c + 8 * q;
        const float* pz = w_hh + (16 * (4 + w) + col) * H + 32 * c + 8 * q;
        const float* pn = w_hh + (16 * (8 + w) + col) * H + 32 * c + 8 * q;
        half8 fr, fz, fn;
#pragma unroll
        for (int j = 0; j < 8; ++j) {
            fr[j] = (_Float16)(-L2E * pr[j]);
            fz[j] = (_Float16)(-L2E * pz[j]);
            fn[j] = (_Float16)( S_N * pn[j]);
        }
        wR[c] = fr; wZ[c] = fz; wN[c] = fn;
    }

    const float bn = S_N * b_hh[2 * H + i];
    const f32x4 Cn = {bn, bn, bn, bn};   // n bias rides the MFMA C operand
    const f32x4 Z  = {0.f, 0.f, 0.f, 0.f};
    f32x4 CrV = Z, CzV = Z;              // elem 0 rewritten per step (row 4q)

    const float wih_r = -L2E * w_ih[i];
    const float wih_z = -L2E * w_ih[H + i];
    const float wih_n =  S_N * w_ih[2 * H + i];
    const float bsr = -L2E * (b_ih[i] + b_hh[i]);
    const float bsz = -L2E * (b_ih[H + i] + b_hh[H + i]);
    const float bin =  S_N * b_ih[2 * H + i];

    // LDS byte offsets (within a parity region)
    char* hbase = (char*)&hB[0][0];
    const int rdA0 = (col >> 2) * 160 + q * 16;  // A0: batch col>>2, k=8q..8q+7
    const int rdA1 = rdA0 + 64;                  // A1: k=32+8q..32+8q+7
    const int wrH  = q * 160 + i * 2;            // write: batch q, value i

    *(_Float16*)(hbase + wrH) = (_Float16)0.0f;  // h0 = 0 (parity 0)
    __syncthreads();

    // x staging: lane's batch q chunk held in 4x f32x4, one chunk prefetched
    const float* xq = x + (size_t)(b0 + q) * TSTEPS;
    f32x4 xe0, xe1, xe2, xe3, xo0, xo1, xo2, xo3;
    xe0 = *(const f32x4*)(xq);      xe1 = *(const f32x4*)(xq + 4);
    xe2 = *(const f32x4*)(xq + 8);  xe3 = *(const f32x4*)(xq + 12);

    float h_reg = 0.0f, hm1 = -1.0f;

#define STEP(tt, XT) {                                                         \
    const int pr_ = ((tt) & 1) * 640;                                          \
    const int pw_ = (((tt) & 1) ^ 1) * 640;                                    \
    const uint4 a0 = *(const uint4*)(hbase + pr_ + rdA0);                      \
    const uint4 a1 = *(const uint4*)(hbase + pr_ + rdA1);                      \
    const float xt_ = (XT);                                                    \
    CrV[0] = fmaf(xt_, wih_r, bsr);     /* under ds_read shadow */             \
    CzV[0] = fmaf(xt_, wih_z, bsz);                                            \
    const float inc = fmaf(xt_, wih_n, bin);                                   \
    const half8 A0 = bc_h8(a0), A1 = bc_h8(a1);                                \
    f32x4 r0 = __builtin_amdgcn_mfma_f32_16x16x32_f16(A0, wR[0], CrV, 0,0,0);  \
    f32x4 r1 = __builtin_amdgcn_mfma_f32_16x16x32_f16(A1, wR[1], Z,   0,0,0);  \
    f32x4 n0 = __builtin_amdgcn_mfma_f32_16x16x32_f16(A0, wN[0], Cn,  0,0,0);  \
    f32x4 n1 = __builtin_amdgcn_mfma_f32_16x16x32_f16(A1, wN[1], Z,   0,0,0);  \
    f32x4 z0 = __builtin_amdgcn_mfma_f32_16x16x32_f16(A0, wZ[0], CzV, 0,0,0);  \
    f32x4 z1 = __builtin_amdgcn_mfma_f32_16x16x32_f16(A1, wZ[1], Z,   0,0,0);  \
    const float er = __builtin_amdgcn_exp2f(r0[0] + r1[0]);                    \
    const float rr = __builtin_amdgcn_rcpf(1.0f + er);                         \
    const float ev = __builtin_amdgcn_exp2f(fmaf(rr, n0[0] + n1[0], inc));     \
    const float uu = __builtin_amdgcn_rcpf(ev + 1.0f);                         \
    const float nn = fmaf(-2.0f, uu, 1.0f);     /* tanh */                     \
    const float ss = fmaf(2.0f, uu, hm1);       /* h-1+2u */                   \
    const float ez = __builtin_amdgcn_exp2f(z0[0] + z1[0]);                    \
    const float zg = __builtin_amdgcn_rcpf(1.0f + ez);                         \
    h_reg = fmaf(zg, ss, nn);                   /* zh + (1-z)n */              \
    hm1 = h_reg - 1.0f;                                                        \
    *(_Float16*)(hbase + pw_ + wrH) = (_Float16)h_reg;                         \
    __syncthreads(); }

#define STEPS16(V0, V1, V2, V3)                                                \
    STEP(0,  V0[0]) STEP(1,  V0[1]) STEP(2,  V0[2]) STEP(3,  V0[3])            \
    STEP(4,  V1[0]) STEP(5,  V1[1]) STEP(6,  V1[2]) STEP(7,  V1[3])            \
    STEP(8,  V2[0]) STEP(9,  V2[1]) STEP(10, V2[2]) STEP(11, V2[3])            \
    STEP(12, V3[0]) STEP(13, V3[1]) STEP(14, V3[2]) STEP(15, V3[3])

    for (int tc = 0; tc < NCHUNK; ++tc) {
        const float* nx = xq + ((tc + 1 < NCHUNK) ? (tc + 1) * XCHUNK : 0);
        if ((tc & 1) == 0) {
            xo0 = *(const f32x4*)(nx);      xo1 = *(const f32x4*)(nx + 4);
            xo2 = *(const f32x4*)(nx + 8);  xo3 = *(const f32x4*)(nx + 12);
            STEPS16(xe0, xe1, xe2, xe3)
        } else {
            xe0 = *(const f32x4*)(nx);      xe1 = *(const f32x4*)(nx + 4);
            xe2 = *(const f32x4*)(nx + 8);  xe3 = *(const f32x4*)(nx + 12);
            STEPS16(xo0, xo1, xo2, xo3)
        }
    }
#undef STEPS16
#undef STEP

    // ---- head: wave w reduces batch w ----
    hf[q][i] = h_reg;                 // 256 threads cover 4x64 slots
    __syncthreads();
    {
        const float hv = hf[w][lane];
#pragma unroll
        for (int cc = 0; cc < CLASSES; ++cc) {
            float v = hv * w_head[cc * H + lane];
#pragma unroll
            for (int off = 32; off > 0; off >>= 1)
                v += __shfl_down(v, off, 64);
            if (lane == 0) out[(b0 + w) * CLASSES + cc] = v + b_head[cc];
        }
    }
}

extern "C" void kernel_launch(void* const* d_in, const int* in_sizes, int n_in,
                              void* d_out, int out_size, void* d_ws, size_t ws_size,
                              hipStream_t stream) {
    const float* x      = (const float*)d_in[0];
    const float* w_ih   = (const float*)d_in[1];
    const float* w_hh   = (const float*)d_in[2];
    const float* b_ih   = (const float*)d_in[3];
    const float* b_hh   = (const float*)d_in[4];
    const float* w_head = (const float*)d_in[5];
    const float* b_head = (const float*)d_in[6];
    float* out = (float*)d_out;

    gru_mfma_kernel<<<NBLK, 256, 0, stream>>>(x, w_ih, w_hh, b_ih, b_hh,
                                              w_head, b_head, out);
}